// Round 11
// baseline (232.737 us; speedup 1.0000x reference)
//
#include <hip/hip_runtime.h>
#include <hip/hip_bf16.h>
#include <math.h>

#define NB   64      // batch
#define D2   64      // objects per batch
#define OBJ  26      // K+2 features per object
#define NQST 11
#define HID  256
#define NOUT 28
#define NTILE 32     // p-pairs per batch; ONE WG per pair-of-p (M=128 rows)
#define MROWS 128

typedef __attribute__((ext_vector_type(8))) short s16x8;
typedef __attribute__((ext_vector_type(4))) float f32x4;
typedef __attribute__((ext_vector_type(2))) unsigned int u32x2;

__device__ __forceinline__ unsigned short f2bf(float f) {
    __hip_bfloat16 h = __float2bfloat16(f);
    union { __hip_bfloat16 h; unsigned short u; } v; v.h = h; return v.u;
}
__device__ __forceinline__ float bf2f(unsigned short h) {
    union { unsigned u; float f; } v; v.u = ((unsigned)h) << 16;
    return v.f;
}
__device__ __forceinline__ unsigned pack_bf2(float a, float b) {
    return ((unsigned)f2bf(a)) | (((unsigned)f2bf(b)) << 16);
}

// ---------------------------------------------------------------------------
// Kernel 1 (merged): blocks 0..767 convert+transpose g2/g3/g4 weights;
// blocks 768..831 compute per-batch A/B from the g1 decomposition:
//   A[q] = o[q] @ g1_w[0:26]
//   B[p] = o[p] @ g1_w[26:52] + qst @ g1_w[52:63] + g1_b
// ---------------------------------------------------------------------------
__global__ __launch_bounds__(256) void prep_all(
        const float* __restrict__ x, const float* __restrict__ qst,
        const float* __restrict__ g1_w, const float* __restrict__ g1_b,
        const float* __restrict__ g2_w, const float* __restrict__ g3_w,
        const float* __restrict__ g4_w,
        unsigned short* __restrict__ Abf, unsigned short* __restrict__ Bbf,
        unsigned short* __restrict__ Wt) {
    if (blockIdx.x < 768) {
        int l = blockIdx.x >> 8;
        int n = blockIdx.x & 255;
        const float* W = (l == 0) ? g2_w : ((l == 1) ? g3_w : g4_w);
        int k = threadIdx.x;
        Wt[(l * HID + n) * HID + k] = f2bf(W[k * HID + n]);
        return;
    }
    int b = blockIdx.x - 768;
    int tid = threadIdx.x;
    __shared__ float o_lds[D2][OBJ];
    for (int idx = tid; idx < 24 * D2; idx += 256) {
        int c = idx >> 6, pos = idx & 63;
        o_lds[pos][c] = x[(b * 24 + c) * D2 + pos];
    }
    if (tid < D2) {
        o_lds[tid][24] = (float)(tid & 7) * (8.0f / 7.0f) - 4.0f;  // cx
        o_lds[tid][25] = (float)(tid >> 3) * (8.0f / 7.0f) - 4.0f; // cy
    }
    __syncthreads();
    int n = tid;  // 0..255
    float qpart = g1_b[n];
    for (int s = 0; s < NQST; ++s)
        qpart += qst[b * NQST + s] * g1_w[(2 * OBJ + s) * HID + n];
    for (int q0 = 0; q0 < D2; q0 += 16) {
        float accA[16], accB[16];
        #pragma unroll
        for (int i = 0; i < 16; ++i) { accA[i] = 0.f; accB[i] = 0.f; }
        for (int c = 0; c < OBJ; ++c) {
            float wA = g1_w[c * HID + n];
            float wB = g1_w[(OBJ + c) * HID + n];
            #pragma unroll
            for (int i = 0; i < 16; ++i) {
                float ov = o_lds[q0 + i][c];
                accA[i] += ov * wA;
                accB[i] += ov * wB;
            }
        }
        #pragma unroll
        for (int i = 0; i < 16; ++i) {
            int q = q0 + i;
            Abf[(b * D2 + q) * HID + n] = f2bf(accA[i]);
            Bbf[(b * D2 + q) * HID + n] = f2bf(accB[i] + qpart);
        }
    }
}

// ---------------------------------------------------------------------------
// rn_main helpers. 1024 threads = 16 waves as 2(m) x 8(n); wave tile 64x32.
// ---------------------------------------------------------------------------

// stage h[m][k] = relu(A[q=m&63][k] + B[p=m>>6][k]), m in [0,128), swizzled.
__device__ __forceinline__ void stage_h(
        unsigned short* hbuf, const unsigned short* __restrict__ Ab,
        const unsigned short* __restrict__ Bb, int tid) {
    #pragma unroll 2
    for (int i = 0; i < 4; ++i) {
        int c = tid + i * 1024;      // 4096 chunks of 8 bf16
        int m = c >> 5;              // 0..127
        int k0 = (c & 31) * 8;
        int q = m & 63;
        int lp = m >> 6;
        s16x8 av = *(const s16x8*)(Ab + q * HID + k0);
        s16x8 bv = *(const s16x8*)(Bb + lp * HID + k0);
        s16x8 hv;
        #pragma unroll
        for (int j = 0; j < 8; j += 2) {
            float f0 = bf2f((unsigned short)av[j])     + bf2f((unsigned short)bv[j]);
            float f1 = bf2f((unsigned short)av[j + 1]) + bf2f((unsigned short)bv[j + 1]);
            unsigned w = pack_bf2(fmaxf(f0, 0.f), fmaxf(f1, 0.f));
            hv[j]     = (short)(w & 0xFFFF);
            hv[j + 1] = (short)(w >> 16);
        }
        int byte = (m * 512 + k0 * 2) ^ ((m & 7) << 4);
        *(s16x8*)((char*)hbuf + byte) = hv;
    }
}

// layers 0/1: swapped-operand mfma(W,h) -> D[n][m]; bias-in-acc; epilogue
// relu+pack -> OTHER buffer (no barrier between K-loop and epilogue).
// acc[2][4] = 32 regs. W loads manually ping-ponged (wA/wB, no reg copies).
__device__ __forceinline__ void layer_sw(
        const unsigned short* __restrict__ Wl, const float* __restrict__ bias,
        const unsigned short* hin, unsigned short* hout,
        int wave_m, int wid_n, int rg, int col) {
    const unsigned short* Ws = Wl + (size_t)(wid_n * 32) * HID;
    f32x4 acc[2][4];   // [nf][mf]
    #pragma unroll
    for (int nf = 0; nf < 2; ++nf) {
        f32x4 b4 = *(const f32x4*)(bias + wid_n * 32 + nf * 16 + rg * 4);
        #pragma unroll
        for (int mf = 0; mf < 4; ++mf)
            acc[nf][mf] = b4;               // bias-in-acc
    }
    s16x8 wA[2], wB[2];
    #pragma unroll
    for (int nf = 0; nf < 2; ++nf)
        wA[nf] = *(const s16x8*)(Ws + (nf * 16 + col) * HID + rg * 8);
    #pragma unroll 1
    for (int kp = 0; kp < 4; ++kp) {
        int ko0 = kp * 64 + rg * 8;
        int ko1 = ko0 + 32;
        #pragma unroll
        for (int nf = 0; nf < 2; ++nf)
            wB[nf] = *(const s16x8*)(Ws + (nf * 16 + col) * HID + ko1);
        {   // even body: uses wA at ko0
            s16x8 hfr[4];
            #pragma unroll
            for (int mf = 0; mf < 4; ++mf) {
                int m = wave_m * 64 + mf * 16 + col;
                int byte = (m * 512 + ko0 * 2) ^ ((m & 7) << 4);
                hfr[mf] = *(const s16x8*)((const char*)hin + byte);
            }
            #pragma unroll
            for (int nf = 0; nf < 2; ++nf)
                #pragma unroll
                for (int mf = 0; mf < 4; ++mf)
                    acc[nf][mf] = __builtin_amdgcn_mfma_f32_16x16x32_bf16(
                        wA[nf], hfr[mf], acc[nf][mf], 0, 0, 0);
        }
        if (kp < 3) {
            int ko2 = ko1 + 32;
            #pragma unroll
            for (int nf = 0; nf < 2; ++nf)
                wA[nf] = *(const s16x8*)(Ws + (nf * 16 + col) * HID + ko2);
        }
        {   // odd body: uses wB at ko1
            s16x8 hfr[4];
            #pragma unroll
            for (int mf = 0; mf < 4; ++mf) {
                int m = wave_m * 64 + mf * 16 + col;
                int byte = (m * 512 + ko1 * 2) ^ ((m & 7) << 4);
                hfr[mf] = *(const s16x8*)((const char*)hin + byte);
            }
            #pragma unroll
            for (int nf = 0; nf < 2; ++nf)
                #pragma unroll
                for (int mf = 0; mf < 4; ++mf)
                    acc[nf][mf] = __builtin_amdgcn_mfma_f32_16x16x32_bf16(
                        wB[nf], hfr[mf], acc[nf][mf], 0, 0, 0);
        }
    }
    // epilogue: n = wid_n*32+nf*16+rg*4+r, m = wave_m*64+mf*16+col -> hout
    #pragma unroll
    for (int nf = 0; nf < 2; ++nf) {
        int n0 = wid_n * 32 + nf * 16 + rg * 4;
        #pragma unroll
        for (int mf = 0; mf < 4; ++mf) {
            int m = wave_m * 64 + mf * 16 + col;
            u32x2 w;
            w[0] = pack_bf2(fmaxf(acc[nf][mf][0], 0.f), fmaxf(acc[nf][mf][1], 0.f));
            w[1] = pack_bf2(fmaxf(acc[nf][mf][2], 0.f), fmaxf(acc[nf][mf][3], 0.f));
            int byte = (m * 512 + n0 * 2) ^ ((m & 7) << 4);
            *(u32x2*)((char*)hout + byte) = w;
        }
    }
}

// layer 2: unswapped mfma(h,W) -> D[m][n]; bias-in-acc; relu + partial sum
// over this wave's 64 rows -> sums[wave_m][n].
__device__ __forceinline__ void layer2_red(
        const unsigned short* __restrict__ Wl, const float* __restrict__ bias,
        const unsigned short* hin, float (*sums)[HID],
        int wave_m, int wid_n, int rg, int col) {
    const unsigned short* Ws = Wl + (size_t)(wid_n * 32) * HID;
    f32x4 acc[4][2];   // [mf][nf]
    #pragma unroll
    for (int nf = 0; nf < 2; ++nf) {
        float bv = bias[wid_n * 32 + nf * 16 + col];
        f32x4 bb = (f32x4){bv, bv, bv, bv};
        #pragma unroll
        for (int mf = 0; mf < 4; ++mf)
            acc[mf][nf] = bb;
    }
    s16x8 wA[2], wB[2];
    #pragma unroll
    for (int nf = 0; nf < 2; ++nf)
        wA[nf] = *(const s16x8*)(Ws + (nf * 16 + col) * HID + rg * 8);
    #pragma unroll 1
    for (int kp = 0; kp < 4; ++kp) {
        int ko0 = kp * 64 + rg * 8;
        int ko1 = ko0 + 32;
        #pragma unroll
        for (int nf = 0; nf < 2; ++nf)
            wB[nf] = *(const s16x8*)(Ws + (nf * 16 + col) * HID + ko1);
        {
            s16x8 hfr[4];
            #pragma unroll
            for (int mf = 0; mf < 4; ++mf) {
                int m = wave_m * 64 + mf * 16 + col;
                int byte = (m * 512 + ko0 * 2) ^ ((m & 7) << 4);
                hfr[mf] = *(const s16x8*)((const char*)hin + byte);
            }
            #pragma unroll
            for (int mf = 0; mf < 4; ++mf)
                #pragma unroll
                for (int nf = 0; nf < 2; ++nf)
                    acc[mf][nf] = __builtin_amdgcn_mfma_f32_16x16x32_bf16(
                        hfr[mf], wA[nf], acc[mf][nf], 0, 0, 0);
        }
        if (kp < 3) {
            int ko2 = ko1 + 32;
            #pragma unroll
            for (int nf = 0; nf < 2; ++nf)
                wA[nf] = *(const s16x8*)(Ws + (nf * 16 + col) * HID + ko2);
        }
        {
            s16x8 hfr[4];
            #pragma unroll
            for (int mf = 0; mf < 4; ++mf) {
                int m = wave_m * 64 + mf * 16 + col;
                int byte = (m * 512 + ko1 * 2) ^ ((m & 7) << 4);
                hfr[mf] = *(const s16x8*)((const char*)hin + byte);
            }
            #pragma unroll
            for (int mf = 0; mf < 4; ++mf)
                #pragma unroll
                for (int nf = 0; nf < 2; ++nf)
                    acc[mf][nf] = __builtin_amdgcn_mfma_f32_16x16x32_bf16(
                        hfr[mf], wB[nf], acc[mf][nf], 0, 0, 0);
        }
    }
    #pragma unroll
    for (int nf = 0; nf < 2; ++nf) {
        float s = 0.f;
        #pragma unroll
        for (int mf = 0; mf < 4; ++mf)
            #pragma unroll
            for (int r = 0; r < 4; ++r)
                s += fmaxf(acc[mf][nf][r], 0.f);
        s += __shfl_xor(s, 16);
        s += __shfl_xor(s, 32);
        if (rg == 0)
            sums[wave_m][wid_n * 32 + nf * 16 + col] = s;
    }
}

// ---------------------------------------------------------------------------
// Kernel 2: main fused g-network, M=128 single pass (both p's of the pair
// concurrently -> no pp loop). 1024 threads = 16 waves (2m x 8n), wave tile
// 64x32 -> acc 32 regs, proven VGPR ~92 at cap 128 (launch_bounds(1024,4);
// mandatory: 1024-thr block needs 4 waves/SIMD resident => <=128 regs).
// Double-buffered h (2 x 64 KiB) + sums (2 KiB) = 130 KiB LDS, 1 block/CU.
// Phase count per 128 pairs: 4 barriers + 3 K-phases = HALF of r10's
// per-pair overhead (the invariant ~205 us across r3/r7/r10 was phase-chain
// bound, not latency/occupancy bound — r7 2w/SIMD == r10 4w/SIMD proved it).
// Manual wA/wB ping-pong kills the 8 reg-copies/ks that pushed VALUBusy
// to 35% in r10.
// ---------------------------------------------------------------------------
__global__ __launch_bounds__(1024, 4) void rn_main(
        const unsigned short* __restrict__ Abf, const unsigned short* __restrict__ Bbf,
        const unsigned short* __restrict__ Wt,
        const float* __restrict__ g2_b, const float* __restrict__ g3_b,
        const float* __restrict__ g4_b, float* __restrict__ partial) {
    // XCD-aware swizzle: 2048 WGs, 8 XCDs (2048 % 8 == 0 -> bijective)
    int wg = blockIdx.x;
    int swz = (wg & 7) * 256 + (wg >> 3);
    int b = swz >> 5;
    int t = swz & 31;

    __shared__ unsigned short h0[MROWS * HID];   // 64 KiB
    __shared__ unsigned short h1[MROWS * HID];   // 64 KiB
    __shared__ float sums[2][HID];               // 2 KiB

    int tid = threadIdx.x;   // 0..1023
    int lane = tid & 63;
    int wid = tid >> 6;      // wave 0..15
    int wave_m = wid >> 3;   // 0..1 -> m-slice of 64
    int wid_n = wid & 7;     // 0..7 -> n-slice of 32
    int rg = lane >> 4;      // 0..3
    int col = lane & 15;

    const unsigned short* Ab = Abf + (size_t)(b * D2) * HID;
    const unsigned short* Bb = Bbf + (size_t)(b * D2 + t * 2) * HID;
    const unsigned short* W0 = Wt;
    const unsigned short* W1 = Wt + (size_t)1 * HID * HID;
    const unsigned short* W2 = Wt + (size_t)2 * HID * HID;

    stage_h(h0, Ab, Bb, tid);
    __syncthreads();                                        // h0 ready
    layer_sw(W0, g2_b, h0, h1, wave_m, wid_n, rg, col);     // r h0 -> w h1
    __syncthreads();                                        // h1 ready
    layer_sw(W1, g3_b, h1, h0, wave_m, wid_n, rg, col);     // r h1 -> w h0
    __syncthreads();                                        // h0 ready
    layer2_red(W2, g4_b, h0, sums, wave_m, wid_n, rg, col); // r h0 -> sums
    __syncthreads();                                        // sums ready

    if (tid < HID)
        partial[(size_t)(b * NTILE + t) * HID + tid] = sums[0][tid] + sums[1][tid];
}

// ---------------------------------------------------------------------------
// Kernel 3: per-batch reduce over tiles + f-network (fp32) + log_softmax
// ---------------------------------------------------------------------------
__global__ __launch_bounds__(256) void fuse_kernel(
        const float* __restrict__ partial,
        const float* __restrict__ f1_w, const float* __restrict__ f1_b,
        const float* __restrict__ f2_w, const float* __restrict__ f2_b,
        const float* __restrict__ f3_w, const float* __restrict__ f3_b,
        float* __restrict__ out) {
    int b = blockIdx.x;
    int tid = threadIdx.x;
    __shared__ float xg[HID];
    __shared__ float h1[HID];
    __shared__ float h2[HID];
    __shared__ float lred[NOUT];
    __shared__ float lse;

    float s = 0.f;
    for (int t = 0; t < NTILE; ++t)
        s += partial[(size_t)(b * NTILE + t) * HID + tid];
    xg[tid] = s;
    __syncthreads();

    float a1 = f1_b[tid];
    for (int k = 0; k < HID; ++k)
        a1 += xg[k] * f1_w[k * HID + tid];
    h1[tid] = a1 > 0.f ? a1 : 0.f;
    __syncthreads();

    float a2 = f2_b[tid];
    for (int k = 0; k < HID; ++k)
        a2 += h1[k] * f2_w[k * HID + tid];
    h2[tid] = a2 > 0.f ? a2 : 0.f;
    __syncthreads();

    float logit = 0.f;
    if (tid < NOUT) {
        logit = f3_b[tid];
        for (int k = 0; k < HID; ++k)
            logit += h2[k] * f3_w[k * NOUT + tid];
        lred[tid] = logit;
    }
    __syncthreads();
    if (tid == 0) {
        float mx = lred[0];
        for (int j = 1; j < NOUT; ++j) mx = fmaxf(mx, lred[j]);
        float se = 0.f;
        for (int j = 0; j < NOUT; ++j) se += expf(lred[j] - mx);
        lse = mx + logf(se);
    }
    __syncthreads();
    if (tid < NOUT)
        out[b * NOUT + tid] = logit - lse;
}

// ---------------------------------------------------------------------------
extern "C" void kernel_launch(void* const* d_in, const int* in_sizes, int n_in,
                              void* d_out, int out_size, void* d_ws, size_t ws_size,
                              hipStream_t stream) {
    const float* x    = (const float*)d_in[0];
    const float* qst  = (const float*)d_in[1];
    const float* g1_w = (const float*)d_in[2];
    const float* g1_b = (const float*)d_in[3];
    const float* g2_w = (const float*)d_in[4];
    const float* g2_b = (const float*)d_in[5];
    const float* g3_w = (const float*)d_in[6];
    const float* g3_b = (const float*)d_in[7];
    const float* g4_w = (const float*)d_in[8];
    const float* g4_b = (const float*)d_in[9];
    const float* f1_w = (const float*)d_in[10];
    const float* f1_b = (const float*)d_in[11];
    const float* f2_w = (const float*)d_in[12];
    const float* f2_b = (const float*)d_in[13];
    const float* f3_w = (const float*)d_in[14];
    const float* f3_b = (const float*)d_in[15];
    float* out = (float*)d_out;

    char* ws = (char*)d_ws;
    unsigned short* Abf = (unsigned short*)ws;                          // 2 MiB
    unsigned short* Bbf = (unsigned short*)(ws + (2u << 20));           // 2 MiB
    unsigned short* Wt  = (unsigned short*)(ws + (4u << 20));           // 384 KiB
    float* partial      = (float*)(ws + (4u << 20) + (512u << 10));     // 2 MiB

    prep_all<<<768 + NB, 256, 0, stream>>>(x, qst, g1_w, g1_b, g2_w, g3_w, g4_w,
                                           Abf, Bbf, Wt);
    rn_main<<<NB * NTILE, 1024, 0, stream>>>(Abf, Bbf, Wt, g2_b, g3_b, g4_b, partial);
    fuse_kernel<<<NB, 256, 0, stream>>>(partial, f1_w, f1_b, f2_w, f2_b, f3_w, f3_b, out);
}

// Round 12
// 199.303 us; speedup vs baseline: 1.1678x; 1.1678x over previous
//
#include <hip/hip_runtime.h>
#include <hip/hip_bf16.h>
#include <math.h>

#define NB   64      // batch
#define D2   64      // objects per batch
#define OBJ  26      // K+2 features per object
#define NQST 11
#define HID  256
#define NOUT 28
#define NTILE 32     // p-tiles per batch (2 p's each, processed sequentially)

typedef __attribute__((ext_vector_type(8))) short s16x8;
typedef __attribute__((ext_vector_type(4))) float f32x4;
typedef __attribute__((ext_vector_type(2))) unsigned int u32x2;

__device__ __forceinline__ unsigned short f2bf(float f) {
    __hip_bfloat16 h = __float2bfloat16(f);
    union { __hip_bfloat16 h; unsigned short u; } v; v.h = h; return v.u;
}
__device__ __forceinline__ float bf2f(unsigned short h) {
    union { unsigned u; float f; } v; v.u = ((unsigned)h) << 16;
    return v.f;
}
__device__ __forceinline__ unsigned pack_bf2(float a, float b) {
    return ((unsigned)f2bf(a)) | (((unsigned)f2bf(b)) << 16);
}

// ---------------------------------------------------------------------------
// Kernel 1 (merged):
// blocks 0..383: FRAG-MAJOR weight repack. Block = ((l*16+nb)*8+ks); the
//   512 bf16 of one wave-fragment-load stored contiguously: element
//   e = lane*8+j holds W_l[k][n], n = nb*16+(lane&15), k = ks*32+(lane>>4)*8+j.
//   In the main kernel a W-frag load is ONE contiguous 1 KB burst at
//   base + ks*1024B (no per-iter address math, L2-prefetch-friendly).
// blocks 384..447: per-batch A/B from the g1 decomposition:
//   A[q] = o[q] @ g1_w[0:26]
//   B[p] = o[p] @ g1_w[26:52] + qst @ g1_w[52:63] + g1_b
// ---------------------------------------------------------------------------
__global__ __launch_bounds__(256) void prep_all(
        const float* __restrict__ x, const float* __restrict__ qst,
        const float* __restrict__ g1_w, const float* __restrict__ g1_b,
        const float* __restrict__ g2_w, const float* __restrict__ g3_w,
        const float* __restrict__ g4_w,
        unsigned short* __restrict__ Abf, unsigned short* __restrict__ Bbf,
        unsigned short* __restrict__ Wt) {
    if (blockIdx.x < 384) {
        int blk = blockIdx.x;
        int ks = blk & 7;
        int nbl = blk >> 3;      // l*16+nb
        int l = nbl >> 4;
        int nb = nbl & 15;
        const float* W = (l == 0) ? g2_w : ((l == 1) ? g3_w : g4_w);
        int t = threadIdx.x;
        #pragma unroll
        for (int u = 0; u < 2; ++u) {
            int e = t + u * 256;             // 0..511
            int lane = e >> 3;
            int j = e & 7;
            int n = nb * 16 + (lane & 15);
            int k = ks * 32 + (lane >> 4) * 8 + j;
            Wt[blk * 512 + e] = f2bf(W[k * HID + n]);
        }
        return;
    }
    int b = blockIdx.x - 384;
    int tid = threadIdx.x;
    __shared__ float o_lds[D2][OBJ];
    for (int idx = tid; idx < 24 * D2; idx += 256) {
        int c = idx >> 6, pos = idx & 63;
        o_lds[pos][c] = x[(b * 24 + c) * D2 + pos];
    }
    if (tid < D2) {
        o_lds[tid][24] = (float)(tid & 7) * (8.0f / 7.0f) - 4.0f;  // cx
        o_lds[tid][25] = (float)(tid >> 3) * (8.0f / 7.0f) - 4.0f; // cy
    }
    __syncthreads();
    int n = tid;  // 0..255
    float qpart = g1_b[n];
    for (int s = 0; s < NQST; ++s)
        qpart += qst[b * NQST + s] * g1_w[(2 * OBJ + s) * HID + n];
    for (int q0 = 0; q0 < D2; q0 += 16) {
        float accA[16], accB[16];
        #pragma unroll
        for (int i = 0; i < 16; ++i) { accA[i] = 0.f; accB[i] = 0.f; }
        for (int c = 0; c < OBJ; ++c) {
            float wA = g1_w[c * HID + n];
            float wB = g1_w[(OBJ + c) * HID + n];
            #pragma unroll
            for (int i = 0; i < 16; ++i) {
                float ov = o_lds[q0 + i][c];
                accA[i] += ov * wA;
                accB[i] += ov * wB;
            }
        }
        #pragma unroll
        for (int i = 0; i < 16; ++i) {
            int q = q0 + i;
            Abf[(b * D2 + q) * HID + n] = f2bf(accA[i]);
            Bbf[(b * D2 + q) * HID + n] = f2bf(accB[i] + qpart);
        }
    }
}

// ---------------------------------------------------------------------------
// rn_main helpers. 256 threads = 4 waves, per-wave n-slice 64.
// ---------------------------------------------------------------------------

// stage h[m][k] = relu(A[m][k] + B[k]) into hbuf (swizzled).
__device__ __forceinline__ void stage_h(
        unsigned short* hbuf, const unsigned short* __restrict__ Ab,
        const unsigned short* __restrict__ Bb, int tid) {
    #pragma unroll 2
    for (int i = 0; i < 8; ++i) {
        int c = tid + i * 256;       // 2048 chunks of 8 bf16
        int m = c >> 5;              // 0..63
        int k0 = (c & 31) * 8;
        s16x8 av = *(const s16x8*)(Ab + m * HID + k0);
        s16x8 bv = *(const s16x8*)(Bb + k0);
        s16x8 hv;
        #pragma unroll
        for (int j = 0; j < 8; j += 2) {
            float f0 = bf2f((unsigned short)av[j])     + bf2f((unsigned short)bv[j]);
            float f1 = bf2f((unsigned short)av[j + 1]) + bf2f((unsigned short)bv[j + 1]);
            unsigned w = pack_bf2(fmaxf(f0, 0.f), fmaxf(f1, 0.f));
            hv[j]     = (short)(w & 0xFFFF);
            hv[j + 1] = (short)(w >> 16);
        }
        int byte = (m * 512 + k0 * 2) ^ ((m & 7) << 4);
        *(s16x8*)((char*)hbuf + byte) = hv;
    }
}

// layers 0/1: swapped-operand mfma(W,h) -> D[n][m]; bias-in-acc; epilogue
// relu+pack -> OTHER buffer (no barrier inside). W loads: frag-major
// contiguous bursts, depth-2 software pipeline (pair double-buffer, 2-ks
// = ~300 cyc lookahead >= L2 latency). setprio(1) around MFMA cluster.
__device__ __forceinline__ void layer_sw(
        const unsigned short* __restrict__ Wl, const float* __restrict__ bias,
        const unsigned short* hin, unsigned short* hout,
        int wid, int rg, int col, int lane) {
    const unsigned short* wb0 = Wl + (size_t)(wid * 4 + 0) * 4096 + lane * 8;
    const unsigned short* wb1 = Wl + (size_t)(wid * 4 + 1) * 4096 + lane * 8;
    const unsigned short* wb2 = Wl + (size_t)(wid * 4 + 2) * 4096 + lane * 8;
    const unsigned short* wb3 = Wl + (size_t)(wid * 4 + 3) * 4096 + lane * 8;

    f32x4 acc[4][4];   // [nf][mf]
    #pragma unroll
    for (int nf = 0; nf < 4; ++nf) {
        f32x4 b4 = *(const f32x4*)(bias + wid * 64 + nf * 16 + rg * 4);
        #pragma unroll
        for (int mf = 0; mf < 4; ++mf)
            acc[nf][mf] = b4;               // bias-in-acc
    }

    s16x8 wbuf[2][2][4];   // [pair parity][ks within pair][nf]
    #pragma unroll
    for (int kk = 0; kk < 2; ++kk) {
        wbuf[0][kk][0] = *(const s16x8*)(wb0 + kk * 512);
        wbuf[0][kk][1] = *(const s16x8*)(wb1 + kk * 512);
        wbuf[0][kk][2] = *(const s16x8*)(wb2 + kk * 512);
        wbuf[0][kk][3] = *(const s16x8*)(wb3 + kk * 512);
    }

    #pragma unroll
    for (int kp = 0; kp < 4; ++kp) {
        const int cur = kp & 1;
        if (kp < 3) {
            #pragma unroll
            for (int kk = 0; kk < 2; ++kk) {
                int off = ((kp + 1) * 2 + kk) * 512;
                wbuf[cur ^ 1][kk][0] = *(const s16x8*)(wb0 + off);
                wbuf[cur ^ 1][kk][1] = *(const s16x8*)(wb1 + off);
                wbuf[cur ^ 1][kk][2] = *(const s16x8*)(wb2 + off);
                wbuf[cur ^ 1][kk][3] = *(const s16x8*)(wb3 + off);
            }
        }
        #pragma unroll
        for (int kk = 0; kk < 2; ++kk) {
            int ko = (kp * 2 + kk) * 32 + rg * 8;
            s16x8 hfr[4];
            #pragma unroll
            for (int mf = 0; mf < 4; ++mf) {
                int m = mf * 16 + col;
                int byte = (m * 512 + ko * 2) ^ ((m & 7) << 4);
                hfr[mf] = *(const s16x8*)((const char*)hin + byte);
            }
            __builtin_amdgcn_s_setprio(1);
            #pragma unroll
            for (int nf = 0; nf < 4; ++nf)
                #pragma unroll
                for (int mf = 0; mf < 4; ++mf)
                    acc[nf][mf] = __builtin_amdgcn_mfma_f32_16x16x32_bf16(
                        wbuf[cur][kk][nf], hfr[mf], acc[nf][mf], 0, 0, 0);
            __builtin_amdgcn_s_setprio(0);
        }
    }
    // epilogue: n = wid*64+nf*16+rg*4+r, m = mf*16+col -> hout
    #pragma unroll
    for (int nf = 0; nf < 4; ++nf) {
        int n0 = wid * 64 + nf * 16 + rg * 4;
        #pragma unroll
        for (int mf = 0; mf < 4; ++mf) {
            int m = mf * 16 + col;
            u32x2 w;
            w[0] = pack_bf2(fmaxf(acc[nf][mf][0], 0.f), fmaxf(acc[nf][mf][1], 0.f));
            w[1] = pack_bf2(fmaxf(acc[nf][mf][2], 0.f), fmaxf(acc[nf][mf][3], 0.f));
            int byte = (m * 512 + n0 * 2) ^ ((m & 7) << 4);
            *(u32x2*)((char*)hout + byte) = w;
        }
    }
}

// layer 2: unswapped mfma(h,W) -> D[m][n]; bias-in-acc; relu + pair-sum.
// Same frag-major depth-2 W pipeline + setprio.
__device__ __forceinline__ void layer2_red(
        const unsigned short* __restrict__ Wl, const float* __restrict__ bias,
        const unsigned short* hin, float* pacc, int wid, int rg, int col, int lane) {
    const unsigned short* wb0 = Wl + (size_t)(wid * 4 + 0) * 4096 + lane * 8;
    const unsigned short* wb1 = Wl + (size_t)(wid * 4 + 1) * 4096 + lane * 8;
    const unsigned short* wb2 = Wl + (size_t)(wid * 4 + 2) * 4096 + lane * 8;
    const unsigned short* wb3 = Wl + (size_t)(wid * 4 + 3) * 4096 + lane * 8;

    f32x4 acc[4][4];   // [mf][nf]
    #pragma unroll
    for (int nf = 0; nf < 4; ++nf) {
        float bv = bias[wid * 64 + nf * 16 + col];
        f32x4 bb = (f32x4){bv, bv, bv, bv};
        #pragma unroll
        for (int mf = 0; mf < 4; ++mf)
            acc[mf][nf] = bb;
    }

    s16x8 wbuf[2][2][4];
    #pragma unroll
    for (int kk = 0; kk < 2; ++kk) {
        wbuf[0][kk][0] = *(const s16x8*)(wb0 + kk * 512);
        wbuf[0][kk][1] = *(const s16x8*)(wb1 + kk * 512);
        wbuf[0][kk][2] = *(const s16x8*)(wb2 + kk * 512);
        wbuf[0][kk][3] = *(const s16x8*)(wb3 + kk * 512);
    }

    #pragma unroll
    for (int kp = 0; kp < 4; ++kp) {
        const int cur = kp & 1;
        if (kp < 3) {
            #pragma unroll
            for (int kk = 0; kk < 2; ++kk) {
                int off = ((kp + 1) * 2 + kk) * 512;
                wbuf[cur ^ 1][kk][0] = *(const s16x8*)(wb0 + off);
                wbuf[cur ^ 1][kk][1] = *(const s16x8*)(wb1 + off);
                wbuf[cur ^ 1][kk][2] = *(const s16x8*)(wb2 + off);
                wbuf[cur ^ 1][kk][3] = *(const s16x8*)(wb3 + off);
            }
        }
        #pragma unroll
        for (int kk = 0; kk < 2; ++kk) {
            int ko = (kp * 2 + kk) * 32 + rg * 8;
            s16x8 hfr[4];
            #pragma unroll
            for (int mf = 0; mf < 4; ++mf) {
                int m = mf * 16 + col;
                int byte = (m * 512 + ko * 2) ^ ((m & 7) << 4);
                hfr[mf] = *(const s16x8*)((const char*)hin + byte);
            }
            __builtin_amdgcn_s_setprio(1);
            #pragma unroll
            for (int mf = 0; mf < 4; ++mf)
                #pragma unroll
                for (int nf = 0; nf < 4; ++nf)
                    acc[mf][nf] = __builtin_amdgcn_mfma_f32_16x16x32_bf16(
                        hfr[mf], wbuf[cur][kk][nf], acc[mf][nf], 0, 0, 0);
            __builtin_amdgcn_s_setprio(0);
        }
    }
    #pragma unroll
    for (int nf = 0; nf < 4; ++nf) {
        float s = 0.f;
        #pragma unroll
        for (int mf = 0; mf < 4; ++mf)
            #pragma unroll
            for (int r = 0; r < 4; ++r)
                s += fmaxf(acc[mf][nf][r], 0.f);
        s += __shfl_xor(s, 16);
        s += __shfl_xor(s, 32);
        pacc[nf] += s;
    }
}

// ---------------------------------------------------------------------------
// Kernel 2: main fused g-network (r7 structure: best measured, 204 us).
// 256 threads = 4 waves, wave n-slice 64, double-buffered h (2x32 KiB),
// 6 barriers per WG, 2 blocks/CU at cap 256 (launch_bounds(256,2)).
// New in r12: frag-major W (1 KB contiguous bursts, ~zero addr VALU),
// depth-2 W prefetch (wbuf[2][2][4], 2-ks lookahead >= L2 latency),
// setprio around MFMA clusters (cross-WG arbitration; 2 independent WGs/CU).
// areg caching dropped: peak live ~170 <= 196 (cap - 60 slack rule).
// ---------------------------------------------------------------------------
__global__ __launch_bounds__(256, 2) void rn_main(
        const unsigned short* __restrict__ Abf, const unsigned short* __restrict__ Bbf,
        const unsigned short* __restrict__ Wt,
        const float* __restrict__ g2_b, const float* __restrict__ g3_b,
        const float* __restrict__ g4_b, float* __restrict__ partial) {
    // XCD-aware swizzle: 2048 WGs, 8 XCDs (2048 % 8 == 0 -> bijective)
    int wg = blockIdx.x;
    int swz = (wg & 7) * 256 + (wg >> 3);
    int b = swz >> 5;
    int t = swz & 31;

    __shared__ unsigned short h0[D2 * HID];   // 32 KiB
    __shared__ unsigned short h1[D2 * HID];   // 32 KiB

    int tid = threadIdx.x;   // 0..255
    int lane = tid & 63;
    int wid = tid >> 6;      // wave 0..3 -> n-slice of 64
    int rg = lane >> 4;      // 0..3
    int col = lane & 15;

    const unsigned short* Ab  = Abf + (size_t)(b * D2) * HID;
    const unsigned short* Bb0 = Bbf + (size_t)(b * D2 + t * 2 + 0) * HID;
    const unsigned short* Bb1 = Bbf + (size_t)(b * D2 + t * 2 + 1) * HID;
    const unsigned short* W0 = Wt;                        // 65536 elems/layer
    const unsigned short* W1 = Wt + (size_t)1 * 65536;
    const unsigned short* W2 = Wt + (size_t)2 * 65536;

    float pacc[4] = {0.f, 0.f, 0.f, 0.f};

    // ---- pp0 ----
    stage_h(h0, Ab, Bb0, tid);
    __syncthreads();                                         // h0 ready
    layer_sw(W0, g2_b, h0, h1, wid, rg, col, lane);          // r h0 -> w h1
    __syncthreads();                                         // h1 ready
    layer_sw(W1, g3_b, h1, h0, wid, rg, col, lane);          // r h1 -> w h0
    __syncthreads();                                         // h0 ready
    layer2_red(W2, g4_b, h0, pacc, wid, rg, col, lane);      // r h0
    stage_h(h1, Ab, Bb1, tid);                               // w h1 (overlaps)
    __syncthreads();                                         // h1 ready

    // ---- pp1 (buffers flipped) ----
    layer_sw(W0, g2_b, h1, h0, wid, rg, col, lane);
    __syncthreads();
    layer_sw(W1, g3_b, h0, h1, wid, rg, col, lane);
    __syncthreads();
    layer2_red(W2, g4_b, h1, pacc, wid, rg, col, lane);

    if (rg == 0) {
        #pragma unroll
        for (int nf = 0; nf < 4; ++nf)
            partial[(size_t)(b * NTILE + t) * HID + wid * 64 + nf * 16 + col]
                = pacc[nf];
    }
}

// ---------------------------------------------------------------------------
// Kernel 3: per-batch reduce over tiles + f-network (fp32) + log_softmax
// ---------------------------------------------------------------------------
__global__ __launch_bounds__(256) void fuse_kernel(
        const float* __restrict__ partial,
        const float* __restrict__ f1_w, const float* __restrict__ f1_b,
        const float* __restrict__ f2_w, const float* __restrict__ f2_b,
        const float* __restrict__ f3_w, const float* __restrict__ f3_b,
        float* __restrict__ out) {
    int b = blockIdx.x;
    int tid = threadIdx.x;
    __shared__ float xg[HID];
    __shared__ float h1[HID];
    __shared__ float h2[HID];
    __shared__ float lred[NOUT];
    __shared__ float lse;

    float s = 0.f;
    for (int t = 0; t < NTILE; ++t)
        s += partial[(size_t)(b * NTILE + t) * HID + tid];
    xg[tid] = s;
    __syncthreads();

    float a1 = f1_b[tid];
    for (int k = 0; k < HID; ++k)
        a1 += xg[k] * f1_w[k * HID + tid];
    h1[tid] = a1 > 0.f ? a1 : 0.f;
    __syncthreads();

    float a2 = f2_b[tid];
    for (int k = 0; k < HID; ++k)
        a2 += h1[k] * f2_w[k * HID + tid];
    h2[tid] = a2 > 0.f ? a2 : 0.f;
    __syncthreads();

    float logit = 0.f;
    if (tid < NOUT) {
        logit = f3_b[tid];
        for (int k = 0; k < HID; ++k)
            logit += h2[k] * f3_w[k * NOUT + tid];
        lred[tid] = logit;
    }
    __syncthreads();
    if (tid == 0) {
        float mx = lred[0];
        for (int j = 1; j < NOUT; ++j) mx = fmaxf(mx, lred[j]);
        float se = 0.f;
        for (int j = 0; j < NOUT; ++j) se += expf(lred[j] - mx);
        lse = mx + logf(se);
    }
    __syncthreads();
    if (tid < NOUT)
        out[b * NOUT + tid] = logit - lse;
}

// ---------------------------------------------------------------------------
extern "C" void kernel_launch(void* const* d_in, const int* in_sizes, int n_in,
                              void* d_out, int out_size, void* d_ws, size_t ws_size,
                              hipStream_t stream) {
    const float* x    = (const float*)d_in[0];
    const float* qst  = (const float*)d_in[1];
    const float* g1_w = (const float*)d_in[2];
    const float* g1_b = (const float*)d_in[3];
    const float* g2_w = (const float*)d_in[4];
    const float* g2_b = (const float*)d_in[5];
    const float* g3_w = (const float*)d_in[6];
    const float* g3_b = (const float*)d_in[7];
    const float* g4_w = (const float*)d_in[8];
    const float* g4_b = (const float*)d_in[9];
    const float* f1_w = (const float*)d_in[10];
    const float* f1_b = (const float*)d_in[11];
    const float* f2_w = (const float*)d_in[12];
    const float* f2_b = (const float*)d_in[13];
    const float* f3_w = (const float*)d_in[14];
    const float* f3_b = (const float*)d_in[15];
    float* out = (float*)d_out;

    char* ws = (char*)d_ws;
    unsigned short* Abf = (unsigned short*)ws;                          // 2 MiB
    unsigned short* Bbf = (unsigned short*)(ws + (2u << 20));           // 2 MiB
    unsigned short* Wt  = (unsigned short*)(ws + (4u << 20));           // 384 KiB
    float* partial      = (float*)(ws + (4u << 20) + (512u << 10));     // 2 MiB

    prep_all<<<384 + NB, 256, 0, stream>>>(x, qst, g1_w, g1_b, g2_w, g3_w, g4_w,
                                           Abf, Bbf, Wt);
    rn_main<<<NB * NTILE, 256, 0, stream>>>(Abf, Bbf, Wt, g2_b, g3_b, g4_b, partial);
    fuse_kernel<<<NB, 256, 0, stream>>>(partial, f1_w, f1_b, f2_w, f2_b, f3_w, f3_b, out);
}

// Round 13
// 159.961 us; speedup vs baseline: 1.4550x; 1.2459x over previous
//
#include <hip/hip_runtime.h>
#include <hip/hip_bf16.h>
#include <math.h>

#define NB   64      // batch
#define D2   64      // objects per batch
#define OBJ  26      // K+2 features per object
#define NQST 11
#define HID  256
#define NOUT 28
#define NTILE 32     // p-tiles per batch (2 p's each, processed sequentially)

typedef __attribute__((ext_vector_type(8))) short s16x8;
typedef __attribute__((ext_vector_type(4))) float f32x4;
typedef __attribute__((ext_vector_type(2))) unsigned int u32x2;

__device__ __forceinline__ unsigned short f2bf(float f) {
    __hip_bfloat16 h = __float2bfloat16(f);
    union { __hip_bfloat16 h; unsigned short u; } v; v.h = h; return v.u;
}
__device__ __forceinline__ float bf2f(unsigned short h) {
    union { unsigned u; float f; } v; v.u = ((unsigned)h) << 16;
    return v.f;
}
__device__ __forceinline__ unsigned pack_bf2(float a, float b) {
    return ((unsigned)f2bf(a)) | (((unsigned)f2bf(b)) << 16);
}

// ---------------------------------------------------------------------------
// Kernel 1 (merged):
// blocks 0..383: FRAG-MAJOR weight repack. Block = ((l*16+nb)*8+ks); the
//   512 bf16 of one wave-fragment-load stored contiguously: element
//   e = lane*8+j holds W_l[k][n], n = nb*16+(lane&15), k = ks*32+(lane>>4)*8+j.
//   Main-kernel W-frag load = ONE contiguous 1 KB burst at base + ks*1024B.
// blocks 384..447: per-batch A/B from the g1 decomposition:
//   A[q] = o[q] @ g1_w[0:26]
//   B[p] = o[p] @ g1_w[26:52] + qst @ g1_w[52:63] + g1_b
// ---------------------------------------------------------------------------
__global__ __launch_bounds__(256) void prep_all(
        const float* __restrict__ x, const float* __restrict__ qst,
        const float* __restrict__ g1_w, const float* __restrict__ g1_b,
        const float* __restrict__ g2_w, const float* __restrict__ g3_w,
        const float* __restrict__ g4_w,
        unsigned short* __restrict__ Abf, unsigned short* __restrict__ Bbf,
        unsigned short* __restrict__ Wt) {
    if (blockIdx.x < 384) {
        int blk = blockIdx.x;
        int ks = blk & 7;
        int nbl = blk >> 3;      // l*16+nb
        int l = nbl >> 4;
        int nb = nbl & 15;
        const float* W = (l == 0) ? g2_w : ((l == 1) ? g3_w : g4_w);
        int t = threadIdx.x;
        #pragma unroll
        for (int u = 0; u < 2; ++u) {
            int e = t + u * 256;             // 0..511
            int lane = e >> 3;
            int j = e & 7;
            int n = nb * 16 + (lane & 15);
            int k = ks * 32 + (lane >> 4) * 8 + j;
            Wt[blk * 512 + e] = f2bf(W[k * HID + n]);
        }
        return;
    }
    int b = blockIdx.x - 384;
    int tid = threadIdx.x;
    __shared__ float o_lds[D2][OBJ];
    for (int idx = tid; idx < 24 * D2; idx += 256) {
        int c = idx >> 6, pos = idx & 63;
        o_lds[pos][c] = x[(b * 24 + c) * D2 + pos];
    }
    if (tid < D2) {
        o_lds[tid][24] = (float)(tid & 7) * (8.0f / 7.0f) - 4.0f;  // cx
        o_lds[tid][25] = (float)(tid >> 3) * (8.0f / 7.0f) - 4.0f; // cy
    }
    __syncthreads();
    int n = tid;  // 0..255
    float qpart = g1_b[n];
    for (int s = 0; s < NQST; ++s)
        qpart += qst[b * NQST + s] * g1_w[(2 * OBJ + s) * HID + n];
    for (int q0 = 0; q0 < D2; q0 += 16) {
        float accA[16], accB[16];
        #pragma unroll
        for (int i = 0; i < 16; ++i) { accA[i] = 0.f; accB[i] = 0.f; }
        for (int c = 0; c < OBJ; ++c) {
            float wA = g1_w[c * HID + n];
            float wB = g1_w[(OBJ + c) * HID + n];
            #pragma unroll
            for (int i = 0; i < 16; ++i) {
                float ov = o_lds[q0 + i][c];
                accA[i] += ov * wA;
                accB[i] += ov * wB;
            }
        }
        #pragma unroll
        for (int i = 0; i < 16; ++i) {
            int q = q0 + i;
            Abf[(b * D2 + q) * HID + n] = f2bf(accA[i]);
            Bbf[(b * D2 + q) * HID + n] = f2bf(accB[i] + qpart);
        }
    }
}

// ---------------------------------------------------------------------------
// rn_main helpers. 256 threads = 4 waves, per-wave n-slice 64.
// ---------------------------------------------------------------------------

// stage h[m][k] = relu(A[m][k] + B[k]) into hbuf (swizzled).
__device__ __forceinline__ void stage_h(
        unsigned short* hbuf, const unsigned short* __restrict__ Ab,
        const unsigned short* __restrict__ Bb, int tid) {
    #pragma unroll 2
    for (int i = 0; i < 8; ++i) {
        int c = tid + i * 256;       // 2048 chunks of 8 bf16
        int m = c >> 5;              // 0..63
        int k0 = (c & 31) * 8;
        s16x8 av = *(const s16x8*)(Ab + m * HID + k0);
        s16x8 bv = *(const s16x8*)(Bb + k0);
        s16x8 hv;
        #pragma unroll
        for (int j = 0; j < 8; j += 2) {
            float f0 = bf2f((unsigned short)av[j])     + bf2f((unsigned short)bv[j]);
            float f1 = bf2f((unsigned short)av[j + 1]) + bf2f((unsigned short)bv[j + 1]);
            unsigned w = pack_bf2(fmaxf(f0, 0.f), fmaxf(f1, 0.f));
            hv[j]     = (short)(w & 0xFFFF);
            hv[j + 1] = (short)(w >> 16);
        }
        int byte = (m * 512 + k0 * 2) ^ ((m & 7) << 4);
        *(s16x8*)((char*)hbuf + byte) = hv;
    }
}

// layers 0/1: swapped-operand mfma(W,h) -> D[n][m]; bias-in-acc; epilogue
// relu+pack -> OTHER buffer. W: frag-major bursts, ks-granularity ping-pong
// (wbuf[2][4] = 32 regs in flight; one ks's 16-MFMA cluster ~310 cyc/SIMD
// >= L2 latency, so depth-1 lookahead suffices — r12's depth-2 (64 regs)
// spilled 160 MB and bought nothing). setprio(1) around MFMA cluster.
__device__ __forceinline__ void layer_sw(
        const unsigned short* __restrict__ Wl, const float* __restrict__ bias,
        const unsigned short* hin, unsigned short* hout,
        int wid, int rg, int col, int lane) {
    const unsigned short* wb0 = Wl + (size_t)(wid * 4 + 0) * 4096 + lane * 8;
    const unsigned short* wb1 = Wl + (size_t)(wid * 4 + 1) * 4096 + lane * 8;
    const unsigned short* wb2 = Wl + (size_t)(wid * 4 + 2) * 4096 + lane * 8;
    const unsigned short* wb3 = Wl + (size_t)(wid * 4 + 3) * 4096 + lane * 8;

    f32x4 acc[4][4];   // [nf][mf]
    #pragma unroll
    for (int nf = 0; nf < 4; ++nf) {
        f32x4 b4 = *(const f32x4*)(bias + wid * 64 + nf * 16 + rg * 4);
        #pragma unroll
        for (int mf = 0; mf < 4; ++mf)
            acc[nf][mf] = b4;               // bias-in-acc
    }

    s16x8 wbuf[2][4];   // ks ping-pong: 32 regs in flight
    wbuf[0][0] = *(const s16x8*)(wb0);
    wbuf[0][1] = *(const s16x8*)(wb1);
    wbuf[0][2] = *(const s16x8*)(wb2);
    wbuf[0][3] = *(const s16x8*)(wb3);

    #pragma unroll
    for (int ks = 0; ks < 8; ++ks) {
        const int cur = ks & 1;
        if (ks < 7) {
            int off = (ks + 1) * 512;
            wbuf[cur ^ 1][0] = *(const s16x8*)(wb0 + off);
            wbuf[cur ^ 1][1] = *(const s16x8*)(wb1 + off);
            wbuf[cur ^ 1][2] = *(const s16x8*)(wb2 + off);
            wbuf[cur ^ 1][3] = *(const s16x8*)(wb3 + off);
        }
        int ko = ks * 32 + rg * 8;
        s16x8 hfr[4];
        #pragma unroll
        for (int mf = 0; mf < 4; ++mf) {
            int m = mf * 16 + col;
            int byte = (m * 512 + ko * 2) ^ ((m & 7) << 4);
            hfr[mf] = *(const s16x8*)((const char*)hin + byte);
        }
        __builtin_amdgcn_s_setprio(1);
        #pragma unroll
        for (int nf = 0; nf < 4; ++nf)
            #pragma unroll
            for (int mf = 0; mf < 4; ++mf)
                acc[nf][mf] = __builtin_amdgcn_mfma_f32_16x16x32_bf16(
                    wbuf[cur][nf], hfr[mf], acc[nf][mf], 0, 0, 0);
        __builtin_amdgcn_s_setprio(0);
    }
    // epilogue: n = wid*64+nf*16+rg*4+r, m = mf*16+col -> hout
    #pragma unroll
    for (int nf = 0; nf < 4; ++nf) {
        int n0 = wid * 64 + nf * 16 + rg * 4;
        #pragma unroll
        for (int mf = 0; mf < 4; ++mf) {
            int m = mf * 16 + col;
            u32x2 w;
            w[0] = pack_bf2(fmaxf(acc[nf][mf][0], 0.f), fmaxf(acc[nf][mf][1], 0.f));
            w[1] = pack_bf2(fmaxf(acc[nf][mf][2], 0.f), fmaxf(acc[nf][mf][3], 0.f));
            int byte = (m * 512 + n0 * 2) ^ ((m & 7) << 4);
            *(u32x2*)((char*)hout + byte) = w;
        }
    }
}

// layer 2: unswapped mfma(h,W) -> D[m][n]; bias-in-acc; relu + pair-sum.
// Same frag-major ks ping-pong + setprio.
__device__ __forceinline__ void layer2_red(
        const unsigned short* __restrict__ Wl, const float* __restrict__ bias,
        const unsigned short* hin, float* pacc, int wid, int rg, int col, int lane) {
    const unsigned short* wb0 = Wl + (size_t)(wid * 4 + 0) * 4096 + lane * 8;
    const unsigned short* wb1 = Wl + (size_t)(wid * 4 + 1) * 4096 + lane * 8;
    const unsigned short* wb2 = Wl + (size_t)(wid * 4 + 2) * 4096 + lane * 8;
    const unsigned short* wb3 = Wl + (size_t)(wid * 4 + 3) * 4096 + lane * 8;

    f32x4 acc[4][4];   // [mf][nf]
    #pragma unroll
    for (int nf = 0; nf < 4; ++nf) {
        float bv = bias[wid * 64 + nf * 16 + col];
        f32x4 bb = (f32x4){bv, bv, bv, bv};
        #pragma unroll
        for (int mf = 0; mf < 4; ++mf)
            acc[mf][nf] = bb;
    }

    s16x8 wbuf[2][4];
    wbuf[0][0] = *(const s16x8*)(wb0);
    wbuf[0][1] = *(const s16x8*)(wb1);
    wbuf[0][2] = *(const s16x8*)(wb2);
    wbuf[0][3] = *(const s16x8*)(wb3);

    #pragma unroll
    for (int ks = 0; ks < 8; ++ks) {
        const int cur = ks & 1;
        if (ks < 7) {
            int off = (ks + 1) * 512;
            wbuf[cur ^ 1][0] = *(const s16x8*)(wb0 + off);
            wbuf[cur ^ 1][1] = *(const s16x8*)(wb1 + off);
            wbuf[cur ^ 1][2] = *(const s16x8*)(wb2 + off);
            wbuf[cur ^ 1][3] = *(const s16x8*)(wb3 + off);
        }
        int ko = ks * 32 + rg * 8;
        s16x8 hfr[4];
        #pragma unroll
        for (int mf = 0; mf < 4; ++mf) {
            int m = mf * 16 + col;
            int byte = (m * 512 + ko * 2) ^ ((m & 7) << 4);
            hfr[mf] = *(const s16x8*)((const char*)hin + byte);
        }
        __builtin_amdgcn_s_setprio(1);
        #pragma unroll
        for (int mf = 0; mf < 4; ++mf)
            #pragma unroll
            for (int nf = 0; nf < 4; ++nf)
                acc[mf][nf] = __builtin_amdgcn_mfma_f32_16x16x32_bf16(
                    hfr[mf], wbuf[cur][nf], acc[mf][nf], 0, 0, 0);
        __builtin_amdgcn_s_setprio(0);
    }
    #pragma unroll
    for (int nf = 0; nf < 4; ++nf) {
        float s = 0.f;
        #pragma unroll
        for (int mf = 0; mf < 4; ++mf)
            #pragma unroll
            for (int r = 0; r < 4; ++r)
                s += fmaxf(acc[mf][nf][r], 0.f);
        s += __shfl_xor(s, 16);
        s += __shfl_xor(s, 32);
        pacc[nf] += s;
    }
}

// ---------------------------------------------------------------------------
// Kernel 2: main fused g-network (r12 structure minus the spill).
// 256 threads = 4 waves, wave n-slice 64, double-buffered h (2x32 KiB),
// 6 barriers per WG, 2 blocks/CU at cap 256 (launch_bounds(256,2)).
// Frag-major W (1 KB contiguous bursts), ks-granularity W ping-pong
// (32 regs in flight), setprio MFMA clusters. Peak live ~142 << 256.
// ---------------------------------------------------------------------------
__global__ __launch_bounds__(256, 2) void rn_main(
        const unsigned short* __restrict__ Abf, const unsigned short* __restrict__ Bbf,
        const unsigned short* __restrict__ Wt,
        const float* __restrict__ g2_b, const float* __restrict__ g3_b,
        const float* __restrict__ g4_b, float* __restrict__ partial) {
    // XCD-aware swizzle: 2048 WGs, 8 XCDs (2048 % 8 == 0 -> bijective)
    int wg = blockIdx.x;
    int swz = (wg & 7) * 256 + (wg >> 3);
    int b = swz >> 5;
    int t = swz & 31;

    __shared__ unsigned short h0[D2 * HID];   // 32 KiB
    __shared__ unsigned short h1[D2 * HID];   // 32 KiB

    int tid = threadIdx.x;   // 0..255
    int lane = tid & 63;
    int wid = tid >> 6;      // wave 0..3 -> n-slice of 64
    int rg = lane >> 4;      // 0..3
    int col = lane & 15;

    const unsigned short* Ab  = Abf + (size_t)(b * D2) * HID;
    const unsigned short* Bb0 = Bbf + (size_t)(b * D2 + t * 2 + 0) * HID;
    const unsigned short* Bb1 = Bbf + (size_t)(b * D2 + t * 2 + 1) * HID;
    const unsigned short* W0 = Wt;                        // 65536 elems/layer
    const unsigned short* W1 = Wt + (size_t)1 * 65536;
    const unsigned short* W2 = Wt + (size_t)2 * 65536;

    float pacc[4] = {0.f, 0.f, 0.f, 0.f};

    // ---- pp0 ----
    stage_h(h0, Ab, Bb0, tid);
    __syncthreads();                                         // h0 ready
    layer_sw(W0, g2_b, h0, h1, wid, rg, col, lane);          // r h0 -> w h1
    __syncthreads();                                         // h1 ready
    layer_sw(W1, g3_b, h1, h0, wid, rg, col, lane);          // r h1 -> w h0
    __syncthreads();                                         // h0 ready
    layer2_red(W2, g4_b, h0, pacc, wid, rg, col, lane);      // r h0
    stage_h(h1, Ab, Bb1, tid);                               // w h1 (overlaps)
    __syncthreads();                                         // h1 ready

    // ---- pp1 (buffers flipped) ----
    layer_sw(W0, g2_b, h1, h0, wid, rg, col, lane);
    __syncthreads();
    layer_sw(W1, g3_b, h0, h1, wid, rg, col, lane);
    __syncthreads();
    layer2_red(W2, g4_b, h1, pacc, wid, rg, col, lane);

    if (rg == 0) {
        #pragma unroll
        for (int nf = 0; nf < 4; ++nf)
            partial[(size_t)(b * NTILE + t) * HID + wid * 64 + nf * 16 + col]
                = pacc[nf];
    }
}

// ---------------------------------------------------------------------------
// Kernel 3: per-batch reduce over tiles + f-network (fp32) + log_softmax
// ---------------------------------------------------------------------------
__global__ __launch_bounds__(256) void fuse_kernel(
        const float* __restrict__ partial,
        const float* __restrict__ f1_w, const float* __restrict__ f1_b,
        const float* __restrict__ f2_w, const float* __restrict__ f2_b,
        const float* __restrict__ f3_w, const float* __restrict__ f3_b,
        float* __restrict__ out) {
    int b = blockIdx.x;
    int tid = threadIdx.x;
    __shared__ float xg[HID];
    __shared__ float h1[HID];
    __shared__ float h2[HID];
    __shared__ float lred[NOUT];
    __shared__ float lse;

    float s = 0.f;
    for (int t = 0; t < NTILE; ++t)
        s += partial[(size_t)(b * NTILE + t) * HID + tid];
    xg[tid] = s;
    __syncthreads();

    float a1 = f1_b[tid];
    for (int k = 0; k < HID; ++k)
        a1 += xg[k] * f1_w[k * HID + tid];
    h1[tid] = a1 > 0.f ? a1 : 0.f;
    __syncthreads();

    float a2 = f2_b[tid];
    for (int k = 0; k < HID; ++k)
        a2 += h1[k] * f2_w[k * HID + tid];
    h2[tid] = a2 > 0.f ? a2 : 0.f;
    __syncthreads();

    float logit = 0.f;
    if (tid < NOUT) {
        logit = f3_b[tid];
        for (int k = 0; k < HID; ++k)
            logit += h2[k] * f3_w[k * NOUT + tid];
        lred[tid] = logit;
    }
    __syncthreads();
    if (tid == 0) {
        float mx = lred[0];
        for (int j = 1; j < NOUT; ++j) mx = fmaxf(mx, lred[j]);
        float se = 0.f;
        for (int j = 0; j < NOUT; ++j) se += expf(lred[j] - mx);
        lse = mx + logf(se);
    }
    __syncthreads();
    if (tid < NOUT)
        out[b * NOUT + tid] = logit - lse;
}

// ---------------------------------------------------------------------------
extern "C" void kernel_launch(void* const* d_in, const int* in_sizes, int n_in,
                              void* d_out, int out_size, void* d_ws, size_t ws_size,
                              hipStream_t stream) {
    const float* x    = (const float*)d_in[0];
    const float* qst  = (const float*)d_in[1];
    const float* g1_w = (const float*)d_in[2];
    const float* g1_b = (const float*)d_in[3];
    const float* g2_w = (const float*)d_in[4];
    const float* g2_b = (const float*)d_in[5];
    const float* g3_w = (const float*)d_in[6];
    const float* g3_b = (const float*)d_in[7];
    const float* g4_w = (const float*)d_in[8];
    const float* g4_b = (const float*)d_in[9];
    const float* f1_w = (const float*)d_in[10];
    const float* f1_b = (const float*)d_in[11];
    const float* f2_w = (const float*)d_in[12];
    const float* f2_b = (const float*)d_in[13];
    const float* f3_w = (const float*)d_in[14];
    const float* f3_b = (const float*)d_in[15];
    float* out = (float*)d_out;

    char* ws = (char*)d_ws;
    unsigned short* Abf = (unsigned short*)ws;                          // 2 MiB
    unsigned short* Bbf = (unsigned short*)(ws + (2u << 20));           // 2 MiB
    unsigned short* Wt  = (unsigned short*)(ws + (4u << 20));           // 384 KiB
    float* partial      = (float*)(ws + (4u << 20) + (512u << 10));     // 2 MiB

    prep_all<<<384 + NB, 256, 0, stream>>>(x, qst, g1_w, g1_b, g2_w, g3_w, g4_w,
                                           Abf, Bbf, Wt);
    rn_main<<<NB * NTILE, 256, 0, stream>>>(Abf, Bbf, Wt, g2_b, g3_b, g4_b, partial);
    fuse_kernel<<<NB, 256, 0, stream>>>(partial, f1_w, f1_b, f2_w, f2_b, f3_w, f3_b, out);
}